// Round 21
// baseline (27.093 us; speedup 1.0000x reference)
//
#include <hip/hip_runtime.h>
#include <math.h>

#define NB 2048
#define ND 784
#define NK 128
#define NSTEP 98           // K = 4d+c -> 3136 = 98 k-steps of 32
#define KSPLIT 16          // K-chunks (variable 6-7 k-steps each)
#define SPKMAX 7
#define MT 128             // rows per k_mm block (8 waves x 16 rows)
#define NHALF 2            // N-split: block does 4 nt = 64 cols

typedef __attribute__((ext_vector_type(8))) short short8;
typedef __attribute__((ext_vector_type(4))) float f32x4;

// ws float offsets: only partials.
#define OFF_PART 0
#define N_PART   (KSPLIT * NB * NK)       // 4,194,304 floats (16.8 MB)

__device__ inline ushort f2bf(float f) {   // round-to-nearest-even f32->bf16
  uint u = __float_as_uint(f);
  return (ushort)((u + 0x7FFFu + ((u >> 16) & 1u)) >> 16);
}

// Fused B-prep + GEMM. Grid = 16 mt x 2 nh x 16 kc = 512 blocks = 2/CU on all
// 256 CUs. 512 threads (8 waves), LDS 57344 B.
// Phase A: cooperative B-slice build into LDS (batched cov/mu loads ->
//   convert; bit-identical table math, fragment-linear layout).
// Phase B: R15-proven loop: x/m prefetch + A-preconvert, then per k-step
//   {8 conflict-free ds_read_b128 -> 12 MFMAs}. Chunk kc covers k-steps
//   [kc*98/16, (kc+1)*98/16) — 6 or 7 steps, guarded.
// acc layout (m89): col = lane&15, row = (lane>>4)*4 + reg.
__global__ __launch_bounds__(512, 4) void k_mm(
    const float* __restrict__ data, const float* __restrict__ mask,
    const float* __restrict__ mu, const float* __restrict__ cov,
    float* __restrict__ ws) {
  __shared__ uint4 BhL[SPKMAX * 4 * 64];   // 28672 B
  __shared__ uint4 BlL[SPKMAX * 4 * 64];   // 28672 B

  float* part = ws + OFF_PART;

  int bid = blockIdx.x;
  int mt  = bid / (NHALF * KSPLIT);
  int rem = bid % (NHALF * KSPLIT);
  int nh  = rem / KSPLIT;
  int kc  = rem % KSPLIT;
  int b0  = (kc * NSTEP) >> 4;        // first k-step of chunk
  int b1  = ((kc + 1) * NSTEP) >> 4;  // one past last
  int nks = b1 - b0;                  // 6 or 7
  int w   = threadIdx.x >> 6;
  int l   = threadIdx.x & 63;
  int r0  = mt * MT + w * 16;
  int rowA = r0 + (l & 15);
  int g2   = (l >> 4) << 1;     // dim offset within k-step: 0,2,4,6
  int n0   = nh * 4;            // block's first nt

  const float* dp = data + (size_t)rowA * ND + g2;
  const float* mp = mask + (size_t)rowA * ND + g2;

  // ---- issue x/m prefetch first (in flight during B staging)
  float2 xs[SPKMAX], ms[SPKMAX];
#pragma unroll
  for (int s = 0; s < SPKMAX; s++) {
    if (s < nks) {
      int ks = b0 + s;
      xs[s] = *(const float2*)(dp + ks * 8);
      ms[s] = *(const float2*)(mp + ks * 8);
    } else {
      xs[s] = make_float2(0.f, 0.f);
      ms[s] = make_float2(0.f, 0.f);
    }
  }

  // ---- Phase A: build B-slice in LDS, batched loads first.
  // Fixed 28-pair indexing (d = b0*8 + 2*dl <= 782, always in-bounds);
  // stores masked to the chunk's actual dl range.
  {
    int d0 = b0 * 8;
    int nb = nh * 64;
    int dlmax = nks * 4;         // valid dim-pairs
    float2 cvv[4], mvv[4];
#pragma unroll
    for (int i = 0; i < 4; i++) {
      int idx = threadIdx.x + i * 512;
      if (idx < 1792) {
        int n  = idx / 28;
        int dl = idx - n * 28;
        int d  = d0 + 2 * dl;
        cvv[i] = *(const float2*)(cov + (size_t)(nb + n) * ND + d);
        mvv[i] = *(const float2*)(mu  + (size_t)(nb + n) * ND + d);
      }
    }
#pragma unroll
    for (int i = 0; i < 4; i++) {
      int idx = threadIdx.x + i * 512;
      if (idx < 1792) {
        int n  = idx / 28;
        int dl = idx - n * 28;
        if (dl < dlmax) {
          float2 cv = cvv[i], mv = mvv[i];
          float va[8];
          va[0] = -0.5f / cv.x;
          va[1] = mv.x / cv.x;
          va[2] = -mv.x * mv.x * 0.5f / cv.x - 0.5f * logf(cv.x);
          va[3] = 0.f;
          va[4] = -0.5f / cv.y;
          va[5] = mv.y / cv.y;
          va[6] = -mv.y * mv.y * 0.5f / cv.y - 0.5f * logf(cv.y);
          va[7] = 0.f;
          ushort hi[8], lo[8];
#pragma unroll
          for (int j = 0; j < 8; j++) {
            ushort h = f2bf(va[j]);
            hi[j] = h;
            lo[j] = f2bf(va[j] - __uint_as_float(((uint)h) << 16));
          }
          uint4 vh, vl;
          vh.x = (uint)hi[0] | ((uint)hi[1] << 16);
          vh.y = (uint)hi[2] | ((uint)hi[3] << 16);
          vh.z = (uint)hi[4] | ((uint)hi[5] << 16);
          vh.w = (uint)hi[6] | ((uint)hi[7] << 16);
          vl.x = (uint)lo[0] | ((uint)lo[1] << 16);
          vl.y = (uint)lo[2] | ((uint)lo[3] << 16);
          vl.z = (uint)lo[4] | ((uint)lo[5] << 16);
          vl.w = (uint)lo[6] | ((uint)lo[7] << 16);
          int ks_l = dl >> 2, lg = dl & 3, ntl = n >> 4, nl = n & 15;
          int fl = ks_l * 4 + ntl;
          int lp = lg * 16 + nl;
          BhL[fl * 64 + lp] = vh;
          BlL[fl * 64 + lp] = vl;
        }
      }
    }
  }

  // ---- A-preconvert (off the k-loop critical path)
  short8 ah[SPKMAX], al[SPKMAX];
#pragma unroll
  for (int s = 0; s < SPKMAX; s++) {
    float2 x = xs[s], m = ms[s];
    float mx0 = m.x * x.x, mq0 = mx0 * x.x;
    float mx1 = m.y * x.y, mq1 = mx1 * x.y;
    ushort h_q0 = f2bf(mq0), h_x0 = f2bf(mx0);
    ushort h_q1 = f2bf(mq1), h_x1 = f2bf(mx1);
    ushort h_m0 = (ushort)(__float_as_uint(m.x) >> 16);  // exact: m in {0,1}
    ushort h_m1 = (ushort)(__float_as_uint(m.y) >> 16);
    float r_q0 = mq0 - __uint_as_float(((uint)h_q0) << 16);
    float r_x0 = mx0 - __uint_as_float(((uint)h_x0) << 16);
    float r_q1 = mq1 - __uint_as_float(((uint)h_q1) << 16);
    float r_x1 = mx1 - __uint_as_float(((uint)h_x1) << 16);
    ah[s][0] = (short)h_q0;       ah[s][1] = (short)h_x0;
    ah[s][2] = (short)h_m0;       ah[s][3] = 0;
    ah[s][4] = (short)h_q1;       ah[s][5] = (short)h_x1;
    ah[s][6] = (short)h_m1;       ah[s][7] = 0;
    al[s][0] = (short)f2bf(r_q0); al[s][1] = (short)f2bf(r_x0);
    al[s][2] = 0;                 al[s][3] = 0;
    al[s][4] = (short)f2bf(r_q1); al[s][5] = (short)f2bf(r_x1);
    al[s][6] = 0;                 al[s][7] = 0;
  }

  __syncthreads();

  f32x4 acc[4];
#pragma unroll
  for (int i = 0; i < 4; i++) acc[i] = (f32x4){0.f, 0.f, 0.f, 0.f};

  const short8* BhS = (const short8*)BhL;
  const short8* BlS = (const short8*)BlL;

#pragma unroll
  for (int s = 0; s < SPKMAX; s++) {
    if (s < nks) {
      // 8 conflict-free ds_read_b128 (consecutive lanes 16B apart)
      short8 b_h0 = BhS[(s * 4 + 0) * 64 + l];
      short8 b_h1 = BhS[(s * 4 + 1) * 64 + l];
      short8 b_h2 = BhS[(s * 4 + 2) * 64 + l];
      short8 b_h3 = BhS[(s * 4 + 3) * 64 + l];
      short8 b_l0 = BlS[(s * 4 + 0) * 64 + l];
      short8 b_l1 = BlS[(s * 4 + 1) * 64 + l];
      short8 b_l2 = BlS[(s * 4 + 2) * 64 + l];
      short8 b_l3 = BlS[(s * 4 + 3) * 64 + l];

      acc[0] = __builtin_amdgcn_mfma_f32_16x16x32_bf16(ah[s], b_h0, acc[0], 0, 0, 0);
      acc[0] = __builtin_amdgcn_mfma_f32_16x16x32_bf16(ah[s], b_l0, acc[0], 0, 0, 0);
      acc[0] = __builtin_amdgcn_mfma_f32_16x16x32_bf16(al[s], b_h0, acc[0], 0, 0, 0);
      acc[1] = __builtin_amdgcn_mfma_f32_16x16x32_bf16(ah[s], b_h1, acc[1], 0, 0, 0);
      acc[1] = __builtin_amdgcn_mfma_f32_16x16x32_bf16(ah[s], b_l1, acc[1], 0, 0, 0);
      acc[1] = __builtin_amdgcn_mfma_f32_16x16x32_bf16(al[s], b_h1, acc[1], 0, 0, 0);
      acc[2] = __builtin_amdgcn_mfma_f32_16x16x32_bf16(ah[s], b_h2, acc[2], 0, 0, 0);
      acc[2] = __builtin_amdgcn_mfma_f32_16x16x32_bf16(ah[s], b_l2, acc[2], 0, 0, 0);
      acc[2] = __builtin_amdgcn_mfma_f32_16x16x32_bf16(al[s], b_h2, acc[2], 0, 0, 0);
      acc[3] = __builtin_amdgcn_mfma_f32_16x16x32_bf16(ah[s], b_h3, acc[3], 0, 0, 0);
      acc[3] = __builtin_amdgcn_mfma_f32_16x16x32_bf16(ah[s], b_l3, acc[3], 0, 0, 0);
      acc[3] = __builtin_amdgcn_mfma_f32_16x16x32_bf16(al[s], b_h3, acc[3], 0, 0, 0);
    }
  }

#pragma unroll
  for (int ntl = 0; ntl < 4; ntl++)
#pragma unroll
    for (int r = 0; r < 4; r++) {
      int grow = r0 + ((l >> 4) << 2) + r;
      part[((size_t)kc * NB + grow) * NK + (n0 + ntl) * 16 + (l & 15)] = acc[ntl][r];
    }
}

// 2 rows per wave, float4 per lane (k-quad). Reduce KSPLIT partials,
// +log w (inline), NaN fix, LSE with the reference's per-term +1e-8
// (4e-8 per lane), exp.
__global__ __launch_bounds__(256) void k_final(
    const float* __restrict__ wts, const float* __restrict__ ws,
    float* __restrict__ out) {
  const float4* part4 = (const float4*)(ws + OFF_PART);
  int lane = threadIdx.x & 63;
  int wv   = threadIdx.x >> 6;
  int half = lane >> 5;
  int lk   = lane & 31;
  int b = blockIdx.x * 8 + wv * 2 + half;

  float4 s = make_float4(0.f, 0.f, 0.f, 0.f);
#pragma unroll
  for (int sp = 0; sp < KSPLIT; sp++) {
    float4 v = part4[((size_t)sp * NB + b) * 32 + lk];
    s.x += v.x; s.y += v.y; s.z += v.z; s.w += v.w;
  }
  float4 wv4 = *(const float4*)(wts + lk * 4);
  s.x += logf(wv4.x); s.y += logf(wv4.y);
  s.z += logf(wv4.z); s.w += logf(wv4.w);
  if (isnan(s.x)) s.x = 0.f;
  if (isnan(s.y)) s.y = 0.f;
  if (isnan(s.z)) s.z = 0.f;
  if (isnan(s.w)) s.w = 0.f;

  float mx = fmaxf(fmaxf(s.x, s.y), fmaxf(s.z, s.w));
#pragma unroll
  for (int off = 16; off; off >>= 1) mx = fmaxf(mx, __shfl_xor(mx, off));
  float sum = expf(s.x - mx) + expf(s.y - mx) + expf(s.z - mx) + expf(s.w - mx) + 4e-8f;
#pragma unroll
  for (int off = 16; off; off >>= 1) sum += __shfl_xor(sum, off);
  float lse = logf(sum) + mx;
  float4 o = make_float4(expf(s.x - lse), expf(s.y - lse),
                         expf(s.z - lse), expf(s.w - lse));
  ((float4*)out)[(size_t)b * 32 + lk] = o;
}

extern "C" void kernel_launch(void* const* d_in, const int* in_sizes, int n_in,
                              void* d_out, int out_size, void* d_ws, size_t ws_size,
                              hipStream_t stream) {
  const float* data = (const float*)d_in[0];
  const float* mask = (const float*)d_in[1];
  const float* wts  = (const float*)d_in[2];
  const float* mu   = (const float*)d_in[3];
  const float* cov  = (const float*)d_in[4];
  float* ws  = (float*)d_ws;
  float* out = (float*)d_out;

  k_mm<<<(NB / MT) * NHALF * KSPLIT, 512, 0, stream>>>(data, mask, mu, cov, ws);
  k_final<<<NB / 8, 256, 0, stream>>>(wts, ws, out);
}

// Round 23
// 23.746 us; speedup vs baseline: 1.1410x; 1.1410x over previous
//
#include <hip/hip_runtime.h>
#include <math.h>

#define NB 2048
#define ND 784
#define NK 128
#define NSTEP 98           // K = 4d+c -> 3136 = 98 k-steps of 32
#define KSPLIT 14          // K-chunks -> partials
#define SPK 7              // k-steps per chunk
#define MT 128             // rows per k_mm block (8 waves x 16 rows)
#define NHALF 2            // N-split: block does 4 nt = 64 cols

typedef __attribute__((ext_vector_type(8))) short short8;
typedef __attribute__((ext_vector_type(4))) float f32x4;

// ws float offsets: only partials.
#define OFF_PART 0
#define N_PART   (KSPLIT * NB * NK)       // 3,670,016 floats (14.7 MB)

__device__ inline ushort f2bf(float f) {   // round-to-nearest-even f32->bf16
  uint u = __float_as_uint(f);
  return (ushort)((u + 0x7FFFu + ((u >> 16) & 1u)) >> 16);
}

// Fused B-prep + GEMM (R20, best measured: 23.8 us total).
// Grid = 16 mt x 2 nh x 14 kc = 448 blocks, 512 threads (8 waves),
// 2 blocks/CU (LDS 57344 B) -> 16 waves/CU.
// Phase A: cooperative B-slice build into LDS (coalesced cov/mu float2 reads,
//   bit-identical table math, fragment-linear layout).
// Phase B: R15-proven loop: x/m prefetch + A-preconvert, then per k-step
//   {8 conflict-free ds_read_b128 -> 12 MFMAs}.
// acc layout (m89): col = lane&15, row = (lane>>4)*4 + reg.
__global__ __launch_bounds__(512, 4) void k_mm(
    const float* __restrict__ data, const float* __restrict__ mask,
    const float* __restrict__ mu, const float* __restrict__ cov,
    float* __restrict__ ws) {
  __shared__ uint4 BhL[SPK * 4 * 64];   // 28672 B
  __shared__ uint4 BlL[SPK * 4 * 64];   // 28672 B

  float* part = ws + OFF_PART;

  int bid = blockIdx.x;
  int mt  = bid / (NHALF * KSPLIT);
  int rem = bid % (NHALF * KSPLIT);
  int nh  = rem / KSPLIT;
  int kc  = rem % KSPLIT;
  int w   = threadIdx.x >> 6;
  int l   = threadIdx.x & 63;
  int r0  = mt * MT + w * 16;
  int rowA = r0 + (l & 15);
  int g2   = (l >> 4) << 1;     // dim offset within k-step: 0,2,4,6
  int n0   = nh * 4;            // block's first nt

  const float* dp = data + (size_t)rowA * ND + g2;
  const float* mp = mask + (size_t)rowA * ND + g2;

  // ---- issue x/m prefetch first (in flight during B staging)
  float2 xs[SPK], ms[SPK];
#pragma unroll
  for (int s = 0; s < SPK; s++) {
    int ks = kc * SPK + s;
    xs[s] = *(const float2*)(dp + ks * 8);
    ms[s] = *(const float2*)(mp + ks * 8);
  }

  // ---- Phase A: build B-slice in LDS.
  // Items: 64 cols x 28 dim-pairs = 1792; thread t handles t, t+512, ...
  {
    int d0 = kc * 56;            // first dim of this kc chunk
    int nb = nh * 64;            // first col of this nh half
#pragma unroll
    for (int i = 0; i < 4; i++) {
      int idx = threadIdx.x + i * 512;
      if (idx < 1792) {
        int n  = idx / 28;       // local col 0..63
        int dl = idx - n * 28;   // local dim-pair 0..27
        int d  = d0 + 2 * dl;
        float2 cv = *(const float2*)(cov + (size_t)(nb + n) * ND + d);
        float2 mv = *(const float2*)(mu  + (size_t)(nb + n) * ND + d);
        float va[8];
        va[0] = -0.5f / cv.x;
        va[1] = mv.x / cv.x;
        va[2] = -mv.x * mv.x * 0.5f / cv.x - 0.5f * logf(cv.x);
        va[3] = 0.f;
        va[4] = -0.5f / cv.y;
        va[5] = mv.y / cv.y;
        va[6] = -mv.y * mv.y * 0.5f / cv.y - 0.5f * logf(cv.y);
        va[7] = 0.f;
        ushort hi[8], lo[8];
#pragma unroll
        for (int j = 0; j < 8; j++) {
          ushort h = f2bf(va[j]);
          hi[j] = h;
          lo[j] = f2bf(va[j] - __uint_as_float(((uint)h) << 16));
        }
        uint4 vh, vl;
        vh.x = (uint)hi[0] | ((uint)hi[1] << 16);
        vh.y = (uint)hi[2] | ((uint)hi[3] << 16);
        vh.z = (uint)hi[4] | ((uint)hi[5] << 16);
        vh.w = (uint)hi[6] | ((uint)hi[7] << 16);
        vl.x = (uint)lo[0] | ((uint)lo[1] << 16);
        vl.y = (uint)lo[2] | ((uint)lo[3] << 16);
        vl.z = (uint)lo[4] | ((uint)lo[5] << 16);
        vl.w = (uint)lo[6] | ((uint)lo[7] << 16);
        int ks_l = dl >> 2, lg = dl & 3, ntl = n >> 4, nl = n & 15;
        int fl = ks_l * 4 + ntl;
        int lp = lg * 16 + nl;
        BhL[fl * 64 + lp] = vh;
        BlL[fl * 64 + lp] = vl;
      }
    }
  }

  // ---- A-preconvert (off the k-loop critical path; overlaps LDS staging tail)
  short8 ah[SPK], al[SPK];
#pragma unroll
  for (int s = 0; s < SPK; s++) {
    float2 x = xs[s], m = ms[s];
    float mx0 = m.x * x.x, mq0 = mx0 * x.x;
    float mx1 = m.y * x.y, mq1 = mx1 * x.y;
    ushort h_q0 = f2bf(mq0), h_x0 = f2bf(mx0);
    ushort h_q1 = f2bf(mq1), h_x1 = f2bf(mx1);
    ushort h_m0 = (ushort)(__float_as_uint(m.x) >> 16);  // exact: m in {0,1}
    ushort h_m1 = (ushort)(__float_as_uint(m.y) >> 16);
    float r_q0 = mq0 - __uint_as_float(((uint)h_q0) << 16);
    float r_x0 = mx0 - __uint_as_float(((uint)h_x0) << 16);
    float r_q1 = mq1 - __uint_as_float(((uint)h_q1) << 16);
    float r_x1 = mx1 - __uint_as_float(((uint)h_x1) << 16);
    ah[s][0] = (short)h_q0;       ah[s][1] = (short)h_x0;
    ah[s][2] = (short)h_m0;       ah[s][3] = 0;
    ah[s][4] = (short)h_q1;       ah[s][5] = (short)h_x1;
    ah[s][6] = (short)h_m1;       ah[s][7] = 0;
    al[s][0] = (short)f2bf(r_q0); al[s][1] = (short)f2bf(r_x0);
    al[s][2] = 0;                 al[s][3] = 0;
    al[s][4] = (short)f2bf(r_q1); al[s][5] = (short)f2bf(r_x1);
    al[s][6] = 0;                 al[s][7] = 0;
  }

  __syncthreads();

  f32x4 acc[4];
#pragma unroll
  for (int i = 0; i < 4; i++) acc[i] = (f32x4){0.f, 0.f, 0.f, 0.f};

  const short8* BhS = (const short8*)BhL;
  const short8* BlS = (const short8*)BlL;

#pragma unroll
  for (int s = 0; s < SPK; s++) {
    // 8 conflict-free ds_read_b128 (consecutive lanes 16B apart)
    short8 b_h0 = BhS[(s * 4 + 0) * 64 + l];
    short8 b_h1 = BhS[(s * 4 + 1) * 64 + l];
    short8 b_h2 = BhS[(s * 4 + 2) * 64 + l];
    short8 b_h3 = BhS[(s * 4 + 3) * 64 + l];
    short8 b_l0 = BlS[(s * 4 + 0) * 64 + l];
    short8 b_l1 = BlS[(s * 4 + 1) * 64 + l];
    short8 b_l2 = BlS[(s * 4 + 2) * 64 + l];
    short8 b_l3 = BlS[(s * 4 + 3) * 64 + l];

    acc[0] = __builtin_amdgcn_mfma_f32_16x16x32_bf16(ah[s], b_h0, acc[0], 0, 0, 0);
    acc[0] = __builtin_amdgcn_mfma_f32_16x16x32_bf16(ah[s], b_l0, acc[0], 0, 0, 0);
    acc[0] = __builtin_amdgcn_mfma_f32_16x16x32_bf16(al[s], b_h0, acc[0], 0, 0, 0);
    acc[1] = __builtin_amdgcn_mfma_f32_16x16x32_bf16(ah[s], b_h1, acc[1], 0, 0, 0);
    acc[1] = __builtin_amdgcn_mfma_f32_16x16x32_bf16(ah[s], b_l1, acc[1], 0, 0, 0);
    acc[1] = __builtin_amdgcn_mfma_f32_16x16x32_bf16(al[s], b_h1, acc[1], 0, 0, 0);
    acc[2] = __builtin_amdgcn_mfma_f32_16x16x32_bf16(ah[s], b_h2, acc[2], 0, 0, 0);
    acc[2] = __builtin_amdgcn_mfma_f32_16x16x32_bf16(ah[s], b_l2, acc[2], 0, 0, 0);
    acc[2] = __builtin_amdgcn_mfma_f32_16x16x32_bf16(al[s], b_h2, acc[2], 0, 0, 0);
    acc[3] = __builtin_amdgcn_mfma_f32_16x16x32_bf16(ah[s], b_h3, acc[3], 0, 0, 0);
    acc[3] = __builtin_amdgcn_mfma_f32_16x16x32_bf16(ah[s], b_l3, acc[3], 0, 0, 0);
    acc[3] = __builtin_amdgcn_mfma_f32_16x16x32_bf16(al[s], b_h3, acc[3], 0, 0, 0);
  }

#pragma unroll
  for (int ntl = 0; ntl < 4; ntl++)
#pragma unroll
    for (int r = 0; r < 4; r++) {
      int grow = r0 + ((l >> 4) << 2) + r;
      part[((size_t)kc * NB + grow) * NK + (n0 + ntl) * 16 + (l & 15)] = acc[ntl][r];
    }
}

// 2 rows per wave, float4 per lane (k-quad). Reduce KSPLIT partials,
// +log w (computed inline), NaN fix, LSE with the reference's per-term
// +1e-8 (4e-8 per lane), exp.
__global__ __launch_bounds__(256) void k_final(
    const float* __restrict__ wts, const float* __restrict__ ws,
    float* __restrict__ out) {
  const float4* part4 = (const float4*)(ws + OFF_PART);
  int lane = threadIdx.x & 63;
  int wv   = threadIdx.x >> 6;
  int half = lane >> 5;
  int lk   = lane & 31;
  int b = blockIdx.x * 8 + wv * 2 + half;

  float4 s = make_float4(0.f, 0.f, 0.f, 0.f);
#pragma unroll
  for (int sp = 0; sp < KSPLIT; sp++) {
    float4 v = part4[((size_t)sp * NB + b) * 32 + lk];
    s.x += v.x; s.y += v.y; s.z += v.z; s.w += v.w;
  }
  float4 wv4 = *(const float4*)(wts + lk * 4);
  s.x += logf(wv4.x); s.y += logf(wv4.y);
  s.z += logf(wv4.z); s.w += logf(wv4.w);
  if (isnan(s.x)) s.x = 0.f;
  if (isnan(s.y)) s.y = 0.f;
  if (isnan(s.z)) s.z = 0.f;
  if (isnan(s.w)) s.w = 0.f;

  float mx = fmaxf(fmaxf(s.x, s.y), fmaxf(s.z, s.w));
#pragma unroll
  for (int off = 16; off; off >>= 1) mx = fmaxf(mx, __shfl_xor(mx, off));
  float sum = expf(s.x - mx) + expf(s.y - mx) + expf(s.z - mx) + expf(s.w - mx) + 4e-8f;
#pragma unroll
  for (int off = 16; off; off >>= 1) sum += __shfl_xor(sum, off);
  float lse = logf(sum) + mx;
  float4 o = make_float4(expf(s.x - lse), expf(s.y - lse),
                         expf(s.z - lse), expf(s.w - lse));
  ((float4*)out)[(size_t)b * 32 + lk] = o;
}

extern "C" void kernel_launch(void* const* d_in, const int* in_sizes, int n_in,
                              void* d_out, int out_size, void* d_ws, size_t ws_size,
                              hipStream_t stream) {
  const float* data = (const float*)d_in[0];
  const float* mask = (const float*)d_in[1];
  const float* wts  = (const float*)d_in[2];
  const float* mu   = (const float*)d_in[3];
  const float* cov  = (const float*)d_in[4];
  float* ws  = (float*)d_ws;
  float* out = (float*)d_out;

  k_mm<<<(NB / MT) * NHALF * KSPLIT, 512, 0, stream>>>(data, mask, mu, cov, ws);
  k_final<<<NB / 8, 256, 0, stream>>>(wts, ws, out);
}